// Round 4
// baseline (296.511 us; speedup 1.0000x reference)
//
#include <hip/hip_runtime.h>
#include <hip/hip_bf16.h>

// GATConv N=50000, C=64, H=12, E=400000 (+N self loops), x-space aggregation:
//   y[d] = concat_h[ (sum_e w_eh x[s_e]) / (den_h*H) ] @ Wstack,  h never built.
// Two launches (+1 memset):
//  k_prep (range-partitioned blocks):
//    build: adj[d][..] = edge ids by dst (cap 64; Poisson(8) in-degree)
//    xb:    bf16(x)
//    wprep: Wt2[c, h*64+k] = bf16(W[k, h*64+c])   (B^T for final GEMM)
//    ax:    a_src/a_dst[n,h] = x[n,:] . v[:,h], v recomputed in-block from W
//  k_fused (16 dst nodes per 256-thr block, 4 waves x 4 nodes):
//    phase1 per node: lane=edge computes 12 softmax weights in parallel
//    phase2 per node: per-edge broadcast via v_readlane (VALU pipe, NOT
//      ds_bpermute -- R3's k_agg was LDS-pipe bound on 12 shfl/edge);
//      denominators accumulate as uniform adds (normalization deferred)
//    z rows -> LDS (stride 776 bf16 = +8 pad), barrier, then 16x64x768 MFMA
//      GEMM (wave = 16-col tile) with fused relu(x + y + bias) epilogue.
// No segment_max: exp(s)/sum exp(s) is exact here (logits O(few), fp32 exp).

typedef __bf16 bf16x8 __attribute__((ext_vector_type(8)));
typedef float f32x4 __attribute__((ext_vector_type(4)));

#define HEADS 12
#define CH 64
#define HC 768
#define CAP 64
#define ZSTRIDE 776   // 768 + 8 bf16 pad -> row-to-row bank shift of 4

__device__ inline float readlane_f(float v, int lane) {
    return __builtin_bit_cast(float,
        __builtin_amdgcn_readlane(__builtin_bit_cast(int, v), lane));
}

__global__ __launch_bounds__(256) void k_prep(
    const float* __restrict__ x, const int* __restrict__ ei,
    const float* __restrict__ W,
    const float* __restrict__ att_src, const float* __restrict__ att_dst,
    int* __restrict__ cnt, int* __restrict__ adj,
    __bf16* __restrict__ xb, __bf16* __restrict__ Wt2,
    float* __restrict__ a_src, float* __restrict__ a_dst,
    int N, int E) {
    const int EP = E + N;
    const int nb_build = (EP + 255) >> 8;
    const int nb_xb    = (N * (CH / 8) + 255) >> 8;
    const int nb_w     = (CH * HC) >> 8;          // 192
    int b = blockIdx.x;

    if (b < nb_build) {                            // ---- adjacency build ----
        int e = b * 256 + threadIdx.x;
        if (e < EP) {
            int d = (e < E) ? ei[E + e] : e - E;
            int pos = atomicAdd(&cnt[d], 1);
            if (pos < CAP) adj[d * CAP + pos] = e;
        }
        return;
    }
    b -= nb_build;
    if (b < nb_xb) {                               // ---- xb = bf16(x) ----
        int t = b * 256 + threadIdx.x;
        if (t < N * (CH / 8)) {
            const float4* xp = (const float4*)x + (size_t)t * 2;
            float4 v0 = xp[0], v1 = xp[1];
            bf16x8 o;
            o[0] = (__bf16)v0.x; o[1] = (__bf16)v0.y;
            o[2] = (__bf16)v0.z; o[3] = (__bf16)v0.w;
            o[4] = (__bf16)v1.x; o[5] = (__bf16)v1.y;
            o[6] = (__bf16)v1.z; o[7] = (__bf16)v1.w;
            ((bf16x8*)xb)[t] = o;
        }
        return;
    }
    b -= nb_xb;
    if (b < nb_w) {                                // ---- Wt2 transpose ----
        int t = b * 256 + threadIdx.x;             // t < CH*HC
        int c = t / HC, kk = t % HC;
        int k = kk & 63;
        Wt2[t] = (__bf16)W[(size_t)k * HC + (kk - k) + c];
        return;
    }
    b -= nb_w;                                     // ---- a_src/a_dst ----
    __shared__ float vs[CH * HEADS], vd[CH * HEADS];
    for (int i = threadIdx.x; i < CH * HEADS; i += 256) {
        int k = i / HEADS, hh = i % HEADS;
        const float* wr  = W + (size_t)k * HC + hh * CH;
        const float* asr = att_src + hh * CH;
        const float* adr = att_dst + hh * CH;
        float s0 = 0.f, s1 = 0.f;
#pragma unroll 8
        for (int c = 0; c < CH; ++c) { float w = wr[c]; s0 += w * asr[c]; s1 += w * adr[c]; }
        vs[i] = s0; vd[i] = s1;
    }
    __syncthreads();
    int n = b * 256 + threadIdx.x;
    if (n >= N) return;
    const f32x4* xr4 = (const f32x4*)(x + (size_t)n * CH);
    float as[HEADS], ad[HEADS];
#pragma unroll
    for (int hh = 0; hh < HEADS; ++hh) { as[hh] = 0.f; ad[hh] = 0.f; }
    for (int k4 = 0; k4 < CH / 4; ++k4) {
        f32x4 xv = xr4[k4];
#pragma unroll
        for (int u = 0; u < 4; ++u) {
            int k = k4 * 4 + u;
#pragma unroll
            for (int hh = 0; hh < HEADS; ++hh) {
                as[hh] += xv[u] * vs[k * HEADS + hh];   // uniform-addr broadcast
                ad[hh] += xv[u] * vd[k * HEADS + hh];
            }
        }
    }
    f32x4* po = (f32x4*)(a_src + (size_t)n * HEADS);
    f32x4* qo = (f32x4*)(a_dst + (size_t)n * HEADS);
#pragma unroll
    for (int g = 0; g < 3; ++g) {
        f32x4 t0, t1;
#pragma unroll
        for (int u = 0; u < 4; ++u) { t0[u] = as[g * 4 + u]; t1[u] = ad[g * 4 + u]; }
        po[g] = t0; qo[g] = t1;
    }
}

__global__ __launch_bounds__(256) void k_fused(
    const int* __restrict__ ei, const int* __restrict__ cnt,
    const int* __restrict__ adj,
    const float* __restrict__ a_src, const float* __restrict__ a_dst,
    const __bf16* __restrict__ xb, const __bf16* __restrict__ Wt2,
    const float* __restrict__ x, const float* __restrict__ bias,
    float* __restrict__ out, int N, int E) {
    __shared__ __bf16 zt[16 * ZSTRIDE];
    int wave = threadIdx.x >> 6, lane = threadIdx.x & 63;
    int base = blockIdx.x * 16;

    for (int j = 0; j < 4; ++j) {
        int row = wave * 4 + j;
        int d = base + row;
        __bf16* zr = zt + row * ZSTRIDE + lane;
        if (d >= N) {
#pragma unroll
            for (int hh = 0; hh < HEADS; ++hh) zr[hh * CH] = (__bf16)0.f;
            continue;
        }
        int deg = cnt[d]; deg = deg < CAP ? deg : CAP;

        // ---- phase 1: lane = edge slot; all weights in parallel ----
        int e_l = (lane < deg) ? adj[d * CAP + lane] : 0;
        int s_l = (e_l < E) ? ei[e_l] : e_l - E;
        if (lane >= deg) s_l = 0;

        float adf[HEADS];
        {
            const f32x4* p = (const f32x4*)(a_dst + (size_t)d * HEADS);
            f32x4 t0 = p[0], t1 = p[1], t2 = p[2];
#pragma unroll
            for (int u = 0; u < 4; ++u) { adf[u] = t0[u]; adf[4 + u] = t1[u]; adf[8 + u] = t2[u]; }
        }
        float w[HEADS];
        if (lane < deg) {
            const f32x4* p = (const f32x4*)(a_src + (size_t)s_l * HEADS);
            f32x4 t0 = p[0], t1 = p[1], t2 = p[2];
            float asf[HEADS];
#pragma unroll
            for (int u = 0; u < 4; ++u) { asf[u] = t0[u]; asf[4 + u] = t1[u]; asf[8 + u] = t2[u]; }
#pragma unroll
            for (int hh = 0; hh < HEADS; ++hh) {
                float sc = asf[hh] + adf[hh];
                sc = sc > 0.f ? sc : 0.2f * sc;
                w[hh] = __expf(sc);
            }
        } else {
#pragma unroll
            for (int hh = 0; hh < HEADS; ++hh) w[hh] = 0.f;
        }

        // ---- phase 2: per-edge broadcast via v_readlane (VALU pipe) ----
        float acc[HEADS], den[HEADS];
#pragma unroll
        for (int hh = 0; hh < HEADS; ++hh) { acc[hh] = 0.f; den[hh] = 0.f; }
        for (int i = 0; i < deg; ++i) {
            int s = __builtin_amdgcn_readlane(s_l, i);
            float xv = (float)xb[(size_t)s * CH + lane];
#pragma unroll
            for (int hh = 0; hh < HEADS; ++hh) {
                float wv = readlane_f(w[hh], i);
                acc[hh] += wv * xv;
                den[hh] += wv;      // uniform across lanes
            }
        }
#pragma unroll
        for (int hh = 0; hh < HEADS; ++hh)
            zr[hh * CH] = (__bf16)(acc[hh] * (1.0f / ((den[hh] + 1e-16f) * HEADS)));
    }

    __syncthreads();

    // ---- phase 3: 16x64x768 GEMM, wave = one 16-col tile ----
    // A[m=lane&15][k=quad*8+j] from LDS; Bt rows of Wt2; D row=quad*4+r, col=lane&15
    int m = lane & 15, quad = lane >> 4;
    int n0 = wave * 16;
    const __bf16* za = zt + m * ZSTRIDE + quad * 8;
    const __bf16* wb = Wt2 + (size_t)(n0 + m) * HC + quad * 8;
    f32x4 acc2 = {0.f, 0.f, 0.f, 0.f};
#pragma unroll
    for (int kc = 0; kc < HC; kc += 32) {
        bf16x8 a = *(const bf16x8*)(za + kc);
        bf16x8 bf = *(const bf16x8*)(wb + kc);
        acc2 = __builtin_amdgcn_mfma_f32_16x16x32_bf16(a, bf, acc2, 0, 0, 0);
    }
    int col = n0 + m;
    float bv = bias[col];
#pragma unroll
    for (int r = 0; r < 4; ++r) {
        int d = base + quad * 4 + r;
        if (d < N) {
            float o = x[(size_t)d * CH + col] + acc2[r] + bv;
            out[(size_t)d * CH + col] = fmaxf(o, 0.f);
        }
    }
}

extern "C" void kernel_launch(void* const* d_in, const int* in_sizes, int n_in,
                              void* d_out, int out_size, void* d_ws, size_t ws_size,
                              hipStream_t stream) {
    const float* x       = (const float*)d_in[0];
    const int*   ei      = (const int*)d_in[1];
    const float* W       = (const float*)d_in[2];
    const float* att_src = (const float*)d_in[3];
    const float* att_dst = (const float*)d_in[4];
    const float* bias    = (const float*)d_in[5];
    float* out = (float*)d_out;

    const int N  = in_sizes[0] / CH;   // 50000
    const int E  = in_sizes[1] / 2;    // 400000
    const int EP = E + N;

    char* ws = (char*)d_ws;
    size_t off = 0;
    auto take = [&](size_t bytes) -> void* {
        void* p = ws + off;
        off = (off + bytes + 255) & ~(size_t)255;
        return p;
    };
    __bf16* xb    = (__bf16*)take((size_t)N * CH * sizeof(__bf16));
    __bf16* Wt2   = (__bf16*)take((size_t)CH * HC * sizeof(__bf16));
    float*  a_src = (float*)take((size_t)N * HEADS * sizeof(float));
    float*  a_dst = (float*)take((size_t)N * HEADS * sizeof(float));
    int*    adj   = (int*)take((size_t)N * CAP * sizeof(int));
    int*    cnt   = (int*)take((size_t)N * sizeof(int));

    hipMemsetAsync(cnt, 0, (size_t)N * sizeof(int), stream);

    const int nb_build = (EP + 255) / 256;
    const int nb_xb    = (N * (CH / 8) + 255) / 256;
    const int nb_w     = (CH * HC) / 256;
    const int nb_ax    = (N + 255) / 256;
    int grid1 = nb_build + nb_xb + nb_w + nb_ax;

    k_prep<<<grid1, 256, 0, stream>>>(x, ei, W, att_src, att_dst,
                                      cnt, adj, xb, Wt2, a_src, a_dst, N, E);
    k_fused<<<(N + 15) / 16, 256, 0, stream>>>(ei, cnt, adj, a_src, a_dst,
                                               xb, Wt2, x, bias, out, N, E);
}

// Round 5
// 216.409 us; speedup vs baseline: 1.3701x; 1.3701x over previous
//
#include <hip/hip_runtime.h>
#include <hip/hip_bf16.h>

// GATConv N=50000, C=64, H=12, E=400000 (+N self loops), x-space aggregation:
//   y[d] = concat_h[ (sum_e w_eh x[s_e]) / (den_h*H) ] @ Wstack,  h never built.
// Launches: memset(cnt) + k_vec + k_prep + k_fused.
//  k_vec (12 blocks): v_src/v_dst[k,h] = sum_c W[k,h*64+c]*att[h,c]. ONCE.
//    (R4 recomputed this per ax-block with 64-way-divergent loads -> 137 us
//     of TA serialization at 1.5% VALUBusy. Never recompute divergent O(1).)
//  k_prep (range-partitioned): build adj (cap 64), xb=bf16(x),
//    Wt2[c,h*64+k]=bf16(W[k,h*64+c]), a_src/a_dst = x . v (v loaded coalesced).
//  k_fused (16 dst/block, 4 waves x 4 nodes):
//    prologue: all 4 nodes' cnt->adj->ei chains issued in parallel
//    per node: lane=edge computes 12 weights; edge loop unrolled x4 so 4
//      xb-row gathers are in flight (readlane broadcast = VALU pipe, no LDS)
//    z rows -> LDS (+8 pad), barrier, 16x64x768 MFMA GEMM, fused
//      relu(x + y + bias) epilogue.
// No segment_max: exp(s)/sum exp(s) is exact here (logits O(few), fp32 exp).

typedef __bf16 bf16x8 __attribute__((ext_vector_type(8)));
typedef float f32x4 __attribute__((ext_vector_type(4)));

#define HEADS 12
#define CH 64
#define HC 768
#define CAP 64
#define ZSTRIDE 776   // 768 + 8 bf16 pad

__device__ inline float readlane_f(float v, int lane) {
    return __builtin_bit_cast(float,
        __builtin_amdgcn_readlane(__builtin_bit_cast(int, v), lane));
}

__global__ void k_vec(const float* __restrict__ W,
                      const float* __restrict__ att_src,
                      const float* __restrict__ att_dst,
                      float* __restrict__ v_src, float* __restrict__ v_dst) {
    int hh = blockIdx.x, k = threadIdx.x;
    const float* wr  = W + (size_t)k * HC + hh * CH;
    const float* asr = att_src + hh * CH;
    const float* adr = att_dst + hh * CH;
    float as = 0.f, ad = 0.f;
#pragma unroll 8
    for (int c = 0; c < CH; ++c) {
        float w = wr[c];
        as += w * asr[c];
        ad += w * adr[c];
    }
    v_src[k * HEADS + hh] = as;
    v_dst[k * HEADS + hh] = ad;
}

__global__ __launch_bounds__(256) void k_prep(
    const float* __restrict__ x, const int* __restrict__ ei,
    const float* __restrict__ W,
    const float* __restrict__ v_src, const float* __restrict__ v_dst,
    int* __restrict__ cnt, int* __restrict__ adj,
    __bf16* __restrict__ xb, __bf16* __restrict__ Wt2,
    float* __restrict__ a_src, float* __restrict__ a_dst,
    int N, int E) {
    const int EP = E + N;
    const int nb_build = (EP + 255) >> 8;
    const int nb_xb    = (N * (CH / 8) + 255) >> 8;
    const int nb_w     = (CH * HC) >> 8;
    int b = blockIdx.x;

    if (b < nb_build) {                            // ---- adjacency build ----
        int e = b * 256 + threadIdx.x;
        if (e < EP) {
            int d = (e < E) ? ei[E + e] : e - E;
            int pos = atomicAdd(&cnt[d], 1);
            if (pos < CAP) adj[d * CAP + pos] = e;
        }
        return;
    }
    b -= nb_build;
    if (b < nb_xb) {                               // ---- xb = bf16(x) ----
        int t = b * 256 + threadIdx.x;
        if (t < N * (CH / 8)) {
            const float4* xp = (const float4*)x + (size_t)t * 2;
            float4 v0 = xp[0], v1 = xp[1];
            bf16x8 o;
            o[0] = (__bf16)v0.x; o[1] = (__bf16)v0.y;
            o[2] = (__bf16)v0.z; o[3] = (__bf16)v0.w;
            o[4] = (__bf16)v1.x; o[5] = (__bf16)v1.y;
            o[6] = (__bf16)v1.z; o[7] = (__bf16)v1.w;
            ((bf16x8*)xb)[t] = o;
        }
        return;
    }
    b -= nb_xb;
    if (b < nb_w) {                                // ---- Wt2 transpose ----
        int t = b * 256 + threadIdx.x;
        int c = t / HC, kk = t % HC;
        int k = kk & 63;
        Wt2[t] = (__bf16)W[(size_t)k * HC + (kk - k) + c];
        return;
    }
    b -= nb_w;                                     // ---- a_src/a_dst ----
    __shared__ float vs[CH * HEADS], vd[CH * HEADS];
    for (int i = threadIdx.x; i < CH * HEADS; i += 256) {  // coalesced load
        vs[i] = v_src[i];
        vd[i] = v_dst[i];
    }
    __syncthreads();
    int n = b * 256 + threadIdx.x;
    if (n >= N) return;
    const f32x4* xr4 = (const f32x4*)(x + (size_t)n * CH);
    float as[HEADS], ad[HEADS];
#pragma unroll
    for (int hh = 0; hh < HEADS; ++hh) { as[hh] = 0.f; ad[hh] = 0.f; }
    for (int k4 = 0; k4 < CH / 4; ++k4) {
        f32x4 xv = xr4[k4];
#pragma unroll
        for (int u = 0; u < 4; ++u) {
            int k = k4 * 4 + u;
#pragma unroll
            for (int hh = 0; hh < HEADS; ++hh) {
                as[hh] += xv[u] * vs[k * HEADS + hh];   // uniform-addr broadcast
                ad[hh] += xv[u] * vd[k * HEADS + hh];
            }
        }
    }
    f32x4* po = (f32x4*)(a_src + (size_t)n * HEADS);
    f32x4* qo = (f32x4*)(a_dst + (size_t)n * HEADS);
#pragma unroll
    for (int g = 0; g < 3; ++g) {
        f32x4 t0, t1;
#pragma unroll
        for (int u = 0; u < 4; ++u) { t0[u] = as[g * 4 + u]; t1[u] = ad[g * 4 + u]; }
        po[g] = t0; qo[g] = t1;
    }
}

__global__ __launch_bounds__(256) void k_fused(
    const int* __restrict__ ei, const int* __restrict__ cnt,
    const int* __restrict__ adj,
    const float* __restrict__ a_src, const float* __restrict__ a_dst,
    const __bf16* __restrict__ xb, const __bf16* __restrict__ Wt2,
    const float* __restrict__ x, const float* __restrict__ bias,
    float* __restrict__ out, int N, int E) {
    __shared__ __bf16 zt[16 * ZSTRIDE];
    int wave = threadIdx.x >> 6, lane = threadIdx.x & 63;
    int base = blockIdx.x * 16;

    // ---- prologue: launch all 4 nodes' cnt->adj->ei chains in parallel ----
    int degj[4], slj[4];
#pragma unroll
    for (int j = 0; j < 4; ++j) {
        int d = base + wave * 4 + j;
        int dg = (d < N) ? cnt[d] : 0;
        dg = dg < CAP ? dg : CAP;
        degj[j] = dg;
        int e = (lane < dg) ? adj[d * CAP + lane] : 0;
        int s = (e < E) ? ei[e] : e - E;
        slj[j] = (lane < dg) ? s : 0;
    }

    for (int j = 0; j < 4; ++j) {
        int row = wave * 4 + j;
        int d = base + row;
        __bf16* zr = zt + row * ZSTRIDE + lane;
        if (d >= N) {
#pragma unroll
            for (int hh = 0; hh < HEADS; ++hh) zr[hh * CH] = (__bf16)0.f;
            continue;
        }
        int deg = degj[j], s_l = slj[j];

        // ---- phase 1: lane = edge slot; all 12 weights in parallel ----
        float adf[HEADS];
        {
            const f32x4* p = (const f32x4*)(a_dst + (size_t)d * HEADS);
            f32x4 t0 = p[0], t1 = p[1], t2 = p[2];
#pragma unroll
            for (int u = 0; u < 4; ++u) { adf[u] = t0[u]; adf[4 + u] = t1[u]; adf[8 + u] = t2[u]; }
        }
        float w[HEADS];
        if (lane < deg) {
            const f32x4* p = (const f32x4*)(a_src + (size_t)s_l * HEADS);
            f32x4 t0 = p[0], t1 = p[1], t2 = p[2];
            float asf[HEADS];
#pragma unroll
            for (int u = 0; u < 4; ++u) { asf[u] = t0[u]; asf[4 + u] = t1[u]; asf[8 + u] = t2[u]; }
#pragma unroll
            for (int hh = 0; hh < HEADS; ++hh) {
                float sc = asf[hh] + adf[hh];
                sc = sc > 0.f ? sc : 0.2f * sc;
                w[hh] = __expf(sc);
            }
        } else {
#pragma unroll
            for (int hh = 0; hh < HEADS; ++hh) w[hh] = 0.f;
        }

        // ---- phase 2: edge loop unrolled x4, readlane broadcast ----
        float acc[HEADS], den[HEADS];
#pragma unroll
        for (int hh = 0; hh < HEADS; ++hh) { acc[hh] = 0.f; den[hh] = 0.f; }
        int i = 0;
        for (; i + 3 < deg; i += 4) {
            int s0 = __builtin_amdgcn_readlane(s_l, i);
            int s1 = __builtin_amdgcn_readlane(s_l, i + 1);
            int s2 = __builtin_amdgcn_readlane(s_l, i + 2);
            int s3 = __builtin_amdgcn_readlane(s_l, i + 3);
            float x0 = (float)xb[(size_t)s0 * CH + lane];
            float x1 = (float)xb[(size_t)s1 * CH + lane];
            float x2 = (float)xb[(size_t)s2 * CH + lane];
            float x3 = (float)xb[(size_t)s3 * CH + lane];
#pragma unroll
            for (int hh = 0; hh < HEADS; ++hh) {
                float w0 = readlane_f(w[hh], i);
                float w1 = readlane_f(w[hh], i + 1);
                float w2 = readlane_f(w[hh], i + 2);
                float w3 = readlane_f(w[hh], i + 3);
                acc[hh] += w0 * x0;
                acc[hh] += w1 * x1;
                acc[hh] += w2 * x2;
                acc[hh] += w3 * x3;
                den[hh] += (w0 + w1) + (w2 + w3);
            }
        }
        for (; i < deg; ++i) {
            int s = __builtin_amdgcn_readlane(s_l, i);
            float xv = (float)xb[(size_t)s * CH + lane];
#pragma unroll
            for (int hh = 0; hh < HEADS; ++hh) {
                float wv = readlane_f(w[hh], i);
                acc[hh] += wv * xv;
                den[hh] += wv;
            }
        }
#pragma unroll
        for (int hh = 0; hh < HEADS; ++hh)
            zr[hh * CH] = (__bf16)(acc[hh] * (1.0f / ((den[hh] + 1e-16f) * HEADS)));
    }

    __syncthreads();

    // ---- phase 3: 16x64x768 GEMM, wave = one 16-col tile ----
    int m = lane & 15, quad = lane >> 4;
    int n0 = wave * 16;
    const __bf16* za = zt + m * ZSTRIDE + quad * 8;
    const __bf16* wb = Wt2 + (size_t)(n0 + m) * HC + quad * 8;
    f32x4 acc2 = {0.f, 0.f, 0.f, 0.f};
#pragma unroll
    for (int kc = 0; kc < HC; kc += 32) {
        bf16x8 a  = *(const bf16x8*)(za + kc);
        bf16x8 bf = *(const bf16x8*)(wb + kc);
        acc2 = __builtin_amdgcn_mfma_f32_16x16x32_bf16(a, bf, acc2, 0, 0, 0);
    }
    int col = n0 + m;
    float bv = bias[col];
#pragma unroll
    for (int r = 0; r < 4; ++r) {
        int d = base + quad * 4 + r;
        if (d < N) {
            float o = x[(size_t)d * CH + col] + acc2[r] + bv;
            out[(size_t)d * CH + col] = fmaxf(o, 0.f);
        }
    }
}

extern "C" void kernel_launch(void* const* d_in, const int* in_sizes, int n_in,
                              void* d_out, int out_size, void* d_ws, size_t ws_size,
                              hipStream_t stream) {
    const float* x       = (const float*)d_in[0];
    const int*   ei      = (const int*)d_in[1];
    const float* W       = (const float*)d_in[2];
    const float* att_src = (const float*)d_in[3];
    const float* att_dst = (const float*)d_in[4];
    const float* bias    = (const float*)d_in[5];
    float* out = (float*)d_out;

    const int N  = in_sizes[0] / CH;   // 50000
    const int E  = in_sizes[1] / 2;    // 400000
    const int EP = E + N;

    char* ws = (char*)d_ws;
    size_t off = 0;
    auto take = [&](size_t bytes) -> void* {
        void* p = ws + off;
        off = (off + bytes + 255) & ~(size_t)255;
        return p;
    };
    __bf16* xb    = (__bf16*)take((size_t)N * CH * sizeof(__bf16));
    __bf16* Wt2   = (__bf16*)take((size_t)CH * HC * sizeof(__bf16));
    float*  v_src = (float*)take(CH * HEADS * sizeof(float));
    float*  v_dst = (float*)take(CH * HEADS * sizeof(float));
    float*  a_src = (float*)take((size_t)N * HEADS * sizeof(float));
    float*  a_dst = (float*)take((size_t)N * HEADS * sizeof(float));
    int*    adj   = (int*)take((size_t)N * CAP * sizeof(int));
    int*    cnt   = (int*)take((size_t)N * sizeof(int));

    hipMemsetAsync(cnt, 0, (size_t)N * sizeof(int), stream);

    const int nb_build = (EP + 255) / 256;
    const int nb_xb    = (N * (CH / 8) + 255) / 256;
    const int nb_w     = (CH * HC) / 256;
    const int nb_ax    = (N + 255) / 256;
    int grid1 = nb_build + nb_xb + nb_w + nb_ax;

    k_vec<<<HEADS, CH, 0, stream>>>(W, att_src, att_dst, v_src, v_dst);
    k_prep<<<grid1, 256, 0, stream>>>(x, ei, W, v_src, v_dst,
                                      cnt, adj, xb, Wt2, a_src, a_dst, N, E);
    k_fused<<<(N + 15) / 16, 256, 0, stream>>>(ei, cnt, adj, a_src, a_dst,
                                               xb, Wt2, x, bias, out, N, E);
}